// Round 14
// baseline (413.053 us; speedup 1.0000x reference)
//
#include <hip/hip_runtime.h>
#include <hip/hip_bf16.h>

#define B_GRAPH 128
#define ETOT    (128*4096)
#define N0G     (128*512)
#define HF      128
// banked stats: [8][256] floats (bank = XCD-ish id) to keep atomics uncontended
#define STSZ    2048

// ---------------- merged: level-0 GEMM (blocks 0..1023) + per-graph init (blocks 1024..1151) ----------------
union IGSmem {
    float Ws[64*HF];                                     // 32 KB (gemm branch)
    struct { int cnt[512]; int cur[512]; float dvl[512]; } ini;
};

__global__ __launch_bounds__(256) void k_init_gemm(
    const float* __restrict__ A, const float* __restrict__ Wg, float* __restrict__ C,
    const int* __restrict__ s_in, const int* __restrict__ d_in_,
    int* __restrict__ srcw, int* __restrict__ dstw, float* __restrict__ wv,
    int2* __restrict__ csr, int2* __restrict__ rb2, float* __restrict__ dinvv,
    float* __restrict__ gacc, float* __restrict__ statsH,
    float* __restrict__ st0, float* __restrict__ st1, float* __restrict__ st2)
{
    __shared__ IGSmem sm;
    int t = threadIdx.x;
    if (blockIdx.x < 1024){
        // XCD-aligned tile: graph tile/8 lands on XCD graph/16 (matches prop's placement)
        int tile = (blockIdx.x & 7)*128 + (blockIdx.x >> 3);
        int tx = t & 15, ty = t >> 4;
        int r0 = tile*64 + ty*4, c0 = tx*4;
        float acc[4][8];
        #pragma unroll
        for (int j=0;j<4;++j)
            #pragma unroll
            for (int l=0;l<8;++l) acc[j][l] = 0.f;
        for (int kh = 0; kh < 2; ++kh){
            __syncthreads();
            {
                float4* d4 = (float4*)sm.Ws;
                const float4* s4 = (const float4*)(Wg + kh*64*HF);
                for (int i = t; i < 64*HF/4; i += 256) d4[i] = s4[i];
            }
            __syncthreads();
            for (int k4 = 0; k4 < 16; ++k4){
                float4 av[4];
                #pragma unroll
                for (int j=0;j<4;++j)
                    av[j] = *(const float4*)(A + (size_t)(r0+j)*HF + kh*64 + k4*4);
                #pragma unroll
                for (int kk=0; kk<4; ++kk){
                    int kl = k4*4 + kk;
                    float4 w0 = *(const float4*)(sm.Ws + kl*HF + c0);
                    float4 w1 = *(const float4*)(sm.Ws + kl*HF + c0 + 64);
                    #pragma unroll
                    for (int j=0;j<4;++j){
                        float a = reinterpret_cast<const float*>(&av[j])[kk];
                        acc[j][0] += a*w0.x; acc[j][1] += a*w0.y; acc[j][2] += a*w0.z; acc[j][3] += a*w0.w;
                        acc[j][4] += a*w1.x; acc[j][5] += a*w1.y; acc[j][6] += a*w1.z; acc[j][7] += a*w1.w;
                    }
                }
            }
        }
        #pragma unroll
        for (int j=0;j<4;++j){
            *(float4*)(C + (size_t)(r0+j)*HF + c0)      = make_float4(acc[j][0],acc[j][1],acc[j][2],acc[j][3]);
            *(float4*)(C + (size_t)(r0+j)*HF + c0 + 64) = make_float4(acc[j][4],acc[j][5],acc[j][6],acc[j][7]);
        }
    } else {
        int b2 = blockIdx.x - 1024;
        int g = (b2 & 7)*16 + (b2 >> 3);      // XCD-aligned: graph g's CSR written on XCD g/16
        for (int l = t; l < 512; l += 256) sm.ini.cnt[l] = 0;
        gacc[g*256 + t] = 0.f;
        if (b2 == 0){
            if (t < 256){ statsH[t] = 0.f; if (t < 128) statsH[256+t] = 0.f; }
            for (int i = t; i < STSZ; i += 256){ st0[i] = 0.f; st1[i] = 0.f; st2[i] = 0.f; }
        }
        __syncthreads();
        for (int j = t; j < 4096; j += 256){
            int e = g*4096 + j;
            int sg = s_in[e], dg = d_in_[e];
            srcw[e] = sg; dstw[e] = dg; wv[e] = 1.f;
            atomicAdd(&sm.ini.cnt[dg & 511], 1);
        }
        __syncthreads();
        int c0 = sm.ini.cnt[2*t], c1 = sm.ini.cnt[2*t+1];
        int pairsum = c0 + c1;
        sm.ini.cur[t] = pairsum;
        __syncthreads();
        for (int off = 1; off < 256; off <<= 1){
            int a = (t >= off) ? sm.ini.cur[t-off] : 0;
            __syncthreads();
            sm.ini.cur[t] += a;
            __syncthreads();
        }
        int begpair = sm.ini.cur[t] - pairsum;
        __syncthreads();
        sm.ini.cur[2*t]   = begpair;
        sm.ini.cur[2*t+1] = begpair + c0;
        __syncthreads();
        for (int l = t; l < 512; l += 256){
            rb2[g*512 + l] = make_int2(g*4096 + sm.ini.cur[l], sm.ini.cnt[l]);
            float dv = rsqrtf((float)sm.ini.cnt[l] + 1.f);
            sm.ini.dvl[l] = dv;
            dinvv[g*512 + l] = dv;
        }
        __syncthreads();
        for (int j = t; j < 4096; j += 256){
            int e = g*4096 + j;
            int sg = srcw[e], dl = dstw[e] & 511;
            int p = atomicAdd(&sm.ini.cur[dl], 1);
            csr[g*4096 + p] = make_int2(sg, __float_as_int(sm.ini.dvl[sg & 511]));
        }
    }
}

// ---------------- chip-wide prop + banked BN stats (level 0, XCD swizzle) ----------------
__global__ __launch_bounds__(256) void k_prop_stats(const float* __restrict__ Y, const float* __restrict__ cb,
                                                    const int2* __restrict__ rb2, const int2* __restrict__ cp,
                                                    const float* __restrict__ dinv,
                                                    float* __restrict__ X, float* __restrict__ st,
                                                    int n, int lb, int Nn){
    __shared__ float rs[1024], rq[1024];
    int xcd = blockIdx.x & 7, c = blockIdx.x >> 3;
    int g = xcd*16 + (c >> lb);
    int m = c & ((1 << lb) - 1);
    int nd = threadIdx.x >> 5;
    int v = g*n + m*8 + nd;
    int f4 = threadIdx.x & 31;
    float dv = dinv[v];
    float4 y = *(const float4*)(Y + (size_t)v*HF + f4*4);
    float4 acc = make_float4(0.f, 0.f, 0.f, 0.f);
    int2 rb = rb2[v];
    int e0 = rb.x, e1 = rb.x + rb.y;
    for (int j = e0; j < e1; ++j){
        int2 e = cp[j];
        int s = e.x & (Nn - 1);
        float en = __int_as_float(e.y);
        float4 h = *(const float4*)(Y + (size_t)s*HF + f4*4);
        acc.x += en*h.x; acc.y += en*h.y; acc.z += en*h.z; acc.w += en*h.w;
    }
    int f = f4*4;
    acc.x = y.x*dv*dv + dv*acc.x + cb[f];
    acc.y = y.y*dv*dv + dv*acc.y + cb[f+1];
    acc.z = y.z*dv*dv + dv*acc.z + cb[f+2];
    acc.w = y.w*dv*dv + dv*acc.w + cb[f+3];
    *(float4*)(X + (size_t)v*HF + f) = acc;
    *(float4*)&rs[nd*HF + f] = acc;
    *(float4*)&rq[nd*HF + f] = make_float4(acc.x*acc.x, acc.y*acc.y, acc.z*acc.z, acc.w*acc.w);
    __syncthreads();
    if (threadIdx.x < 128){
        int tt = threadIdx.x;
        float s = 0.f, q = 0.f;
        #pragma unroll
        for (int j = 0; j < 8; ++j){ s += rs[j*HF + tt]; q += rq[j*HF + tt]; }
        atomicAdd(&st[xcd*256 + tt], s);
        atomicAdd(&st[xcd*256 + 128 + tt], q);
    }
}

// ---------------- mega-fused per-graph kernel + conv tail + (L4) head1 tail ----------------
union __align__(16) KSmem {
    struct {
        int2  eds[4096]; int2 rbl[512];
        float dvv[512], p0[512], p1[512], p2[512];
        float ss[512]; int si[512]; float tss[256]; int nid[512];
        int   cntN[256], curN[256]; float dvn[256];
        float bna[128], bnb[128]; float red[1024]; float awl[128];
    } gr;
    struct { float Ws[64*HF]; float red[32*HF]; } cv;
};

__global__ __launch_bounds__(1024) void k_graph(
    const float* __restrict__ H, const float* __restrict__ stats,
    const float* __restrict__ gw, const float* __restrict__ gb,
    const float* __restrict__ aw, const float* __restrict__ th,
    const int2* __restrict__ rb2, int2* __restrict__ csr, const float* __restrict__ dinv,
    int* __restrict__ srcw, int* __restrict__ dstw, float* __restrict__ wv,
    float* __restrict__ P, float* __restrict__ gacc,
    int2* __restrict__ rb2n, float* __restrict__ dinvn,
    float* __restrict__ stZero, float* __restrict__ stAcc,
    const float* __restrict__ Wnext, const float* __restrict__ cbNext,
    float* __restrict__ Gnext, float* __restrict__ Hnext,
    const float* __restrict__ lin1W, const float* __restrict__ lin1b,
    float* __restrict__ t1g, float* __restrict__ statsH,
    float invN, float ca2, float cc2, float ca3, float cc3,
    int n, int last)
{
    int b = blockIdx.x, t = threadIdx.x;
    int g = (b & 7)*16 + (b >> 3);            // XCD-aligned: block for graph g lands on XCD g/16
    int k = n >> 1;
    __shared__ KSmem sm;

    if (t < 256) stZero[(g & 7)*256 + t] = 0.f;
    if (t < 128){
        float s = 0.f, q = 0.f;
        #pragma unroll
        for (int b2 = 0; b2 < 8; ++b2){ s += stats[b2*256 + t]; q += stats[b2*256 + 128 + t]; }
        float mean = s*invN;
        float var  = q*invN - mean*mean;
        float iv   = rsqrtf(var + 1e-5f);
        sm.gr.bna[t] = iv*gw[t];
        sm.gr.bnb[t] = gb[t] - mean*iv*gw[t];
        sm.gr.awl[t] = aw[t];
    }
    for (int l = t; l < n; l += 1024){
        int2 rb = rb2[g*n + l];
        sm.gr.rbl[l] = make_int2(rb.x - g*4096, rb.y);
        sm.gr.dvv[l] = dinv[g*n + l];
    }
    __syncthreads();
    int medg = sm.gr.rbl[n-1].x + sm.gr.rbl[n-1].y;
    for (int j = t; j < medg; j += 1024){
        int2 e = csr[g*4096 + j];
        sm.gr.eds[j] = make_int2(e.x & (n-1), e.y);
    }
    // ---- s0: 2 threads per node, float4 loads ----
    {
        int l = t >> 1, h = t & 1;
        float part = 0.f;
        if (l < n){
            const float* hp = H + ((size_t)g*n + l)*HF + h*64;
            #pragma unroll
            for (int j = 0; j < 16; ++j){
                float4 v = *(const float4*)(hp + j*4);
                int f = h*64 + j*4;
                float4 a4 = *(const float4*)&sm.gr.bna[f];
                float4 b4 = *(const float4*)&sm.gr.bnb[f];
                float4 w4 = *(const float4*)&sm.gr.awl[f];
                part += fmaxf(v.x*a4.x + b4.x, 0.f)*w4.x
                      + fmaxf(v.y*a4.y + b4.y, 0.f)*w4.y
                      + fmaxf(v.z*a4.z + b4.z, 0.f)*w4.z
                      + fmaxf(v.w*a4.w + b4.w, 0.f)*w4.w;
            }
        }
        sm.gr.red[t] = part;
    }
    __syncthreads();
    for (int l = t; l < n; l += 1024) sm.gr.p0[l] = sm.gr.red[2*l] + sm.gr.red[2*l+1];
    __syncthreads();
    for (int l = t; l < n; l += 1024){
        int2 rc = sm.gr.rbl[l];
        float acc = 0.f;
        for (int j = 0; j < rc.y; ++j){
            int2 e = sm.gr.eds[rc.x + j];
            acc += __int_as_float(e.y) * sm.gr.p0[e.x];
        }
        float dv = sm.gr.dvv[l];
        sm.gr.p1[l] = 2.f*(sm.gr.p0[l]*dv*dv + dv*acc);
    }
    __syncthreads();
    for (int l = t; l < n; l += 1024){
        int2 rc = sm.gr.rbl[l];
        float acc = 0.f;
        for (int j = 0; j < rc.y; ++j){
            int2 e = sm.gr.eds[rc.x + j];
            acc += __int_as_float(e.y) * sm.gr.p1[e.x];
        }
        float dv = sm.gr.dvv[l];
        sm.gr.p2[l] = ca2*(sm.gr.p1[l]*dv*dv + dv*acc) + cc2*sm.gr.p0[l];
    }
    __syncthreads();
    float t0v = th[0], t1v = th[1], t2c = th[2], t3v = th[3];
    for (int l = t; l < n; l += 1024){
        int2 rc = sm.gr.rbl[l];
        float acc = 0.f;
        for (int j = 0; j < rc.y; ++j){
            int2 e = sm.gr.eds[rc.x + j];
            acc += __int_as_float(e.y) * sm.gr.p2[e.x];
        }
        float dv = sm.gr.dvv[l];
        float tv = sm.gr.p2[l]*dv*dv + dv*acc;
        float p3 = ca3*tv + cc3*sm.gr.p1[l];
        sm.gr.ss[l] = t0v*sm.gr.p0[l] + t1v*sm.gr.p1[l] + t2c*sm.gr.p2[l] + t3v*p3;
        sm.gr.si[l] = l;
    }
    __syncthreads();
    for (int size = 2; size <= n; size <<= 1){
        for (int stride = size >> 1; stride > 0; stride >>= 1){
            for (int i = t; i < n; i += 1024){
                int j = i ^ stride;
                if (j > i){
                    bool asc = ((i & size) == 0);
                    float s1 = sm.gr.ss[i], s2 = sm.gr.ss[j];
                    int   i1 = sm.gr.si[i], i2 = sm.gr.si[j];
                    bool gt = (s1 < s2) || (s1 == s2 && i1 > i2);
                    if (gt == asc){ sm.gr.ss[i] = s2; sm.gr.ss[j] = s1; sm.gr.si[i] = i2; sm.gr.si[j] = i1; }
                }
            }
            __syncthreads();
        }
    }
    for (int l = t; l < n; l += 1024) sm.gr.nid[l] = -1;
    __syncthreads();
    for (int r = t; r < k; r += 1024){
        sm.gr.nid[sm.gr.si[r]] = r;
        sm.gr.tss[r] = tanhf(sm.gr.ss[r]);
    }
    __syncthreads();
    // ---- gather (BN+ReLU+tanh scale) + readout, float4 throughout ----
    {
        int f4 = t & 31, rl = t >> 5;
        int f = f4*4;
        float4 a4 = *(const float4*)&sm.gr.bna[f];
        float4 b4 = *(const float4*)&sm.gr.bnb[f];
        float4 mx = make_float4(-3.4e38f,-3.4e38f,-3.4e38f,-3.4e38f);
        float4 smv = make_float4(0.f,0.f,0.f,0.f);
        for (int r = rl; r < k; r += 32){
            int old = sm.gr.si[r];
            float4 hv = *(const float4*)(H + ((size_t)g*n + old)*HF + f);
            float ts = sm.gr.tss[r];
            float4 v;
            v.x = fmaxf(hv.x*a4.x + b4.x, 0.f)*ts;
            v.y = fmaxf(hv.y*a4.y + b4.y, 0.f)*ts;
            v.z = fmaxf(hv.z*a4.z + b4.z, 0.f)*ts;
            v.w = fmaxf(hv.w*a4.w + b4.w, 0.f)*ts;
            *(float4*)(P + ((size_t)g*k + r)*HF + f) = v;
            mx.x = fmaxf(mx.x, v.x); mx.y = fmaxf(mx.y, v.y);
            mx.z = fmaxf(mx.z, v.z); mx.w = fmaxf(mx.w, v.w);
            smv.x += v.x; smv.y += v.y; smv.z += v.z; smv.w += v.w;
        }
        float* scr = (float*)sm.gr.eds;
        *(float4*)&scr[rl*128 + f]        = mx;
        *(float4*)&scr[4096 + rl*128 + f] = smv;
        __syncthreads();
        if (t < 128){
            float m = -3.4e38f, s = 0.f;
            #pragma unroll
            for (int j = 0; j < 32; ++j){
                m = fmaxf(m, scr[j*128 + t]);
                s += scr[4096 + j*128 + t];
            }
            gacc[g*256 + t] += m;
            gacc[g*256 + 128 + t] += s / (float)k;
        }
    }
    if (last){
        // ======== head1 tail ========
        __syncthreads();
        int c = t & 127, h = t >> 7;
        float s = 0.f;
        int k0 = h*32;
        #pragma unroll
        for (int kk = 0; kk < 32; ++kk)
            s += gacc[g*256 + k0 + kk] * lin1W[(k0 + kk)*128 + c];
        sm.gr.red[t] = s;
        __syncthreads();
        if (t < 512) sm.gr.red[t] += sm.gr.red[t+512];
        __syncthreads();
        if (t < 256) sm.gr.red[t] += sm.gr.red[t+256];
        __syncthreads();
        if (t < 128){
            float v = (sm.gr.red[t] + sm.gr.red[t+128]) * 0.2f + lin1b[t];
            t1g[g*128 + t] = v;
            atomicAdd(&statsH[t], v);
            atomicAdd(&statsH[128+t], v*v);
        }
        return;
    }
    __syncthreads();
    // ---- remap + next-level CSR ----
    if (t < k) sm.gr.cntN[t] = 0;
    __syncthreads();
    for (int j = t; j < 4096; j += 1024){
        int e = g*4096 + j;
        float we = wv[e];
        int valid = 0, ns = 0, nd = 0;
        if (we > 0.5f){
            int sl = srcw[e] & (n-1);
            int dl = dstw[e] & (n-1);
            ns = sm.gr.nid[sl]; nd = sm.gr.nid[dl];
            valid = (ns >= 0) && (nd >= 0);
        }
        if (valid){
            srcw[e] = g*k + ns; dstw[e] = g*k + nd; wv[e] = 1.f;
            atomicAdd(&sm.gr.cntN[nd], 1);
        } else {
            srcw[e] = 0; dstw[e] = 0; wv[e] = 0.f;
        }
    }
    __syncthreads();
    int c = (t < 256) ? ((t < k) ? sm.gr.cntN[t] : 0) : 0;
    if (t < 256) sm.gr.si[t] = c;
    __syncthreads();
    for (int off = 1; off < 256; off <<= 1){
        int a = 0;
        if (t < 256 && t >= off) a = sm.gr.si[t-off];
        __syncthreads();
        if (t < 256) sm.gr.si[t] += a;
        __syncthreads();
    }
    if (t < k){
        int beg = sm.gr.si[t] - c;
        rb2n[g*k + t] = make_int2(g*4096 + beg, c);
        float dv = rsqrtf((float)c + 1.f);
        dinvn[g*k + t] = dv;
        sm.gr.dvn[t] = dv;
        sm.gr.curN[t] = beg;
    }
    __syncthreads();
    for (int j = t; j < 4096; j += 1024){
        int e = g*4096 + j;
        if (wv[e] > 0.5f){
            int sg = srcw[e], dl = dstw[e] & (k-1);
            int p = atomicAdd(&sm.gr.curN[dl], 1);
            csr[g*4096 + p] = make_int2(sg, __float_as_int(sm.gr.dvn[sg & (k-1)]));
        }
    }
    __syncthreads();
    // ======== conv tail for level L+1 ========
    int Nn2 = B_GRAPH * k;
    {
        int sub = t >> 8, t8 = t & 255, tx = t8 & 15, ty = t8 >> 4;
        int cc0 = tx*4;
        int nT = (k + 255) >> 8;
        for (int tile = 0; tile < nT; ++tile){
            int r0 = tile*256 + sub*64 + ty*4;
            bool act = (r0 < k);
            float acc[4][8];
            #pragma unroll
            for (int j=0;j<4;++j)
                #pragma unroll
                for (int l=0;l<8;++l) acc[j][l] = 0.f;
            for (int kh = 0; kh < 2; ++kh){
                __syncthreads();
                {
                    float4* d4 = (float4*)sm.cv.Ws;
                    const float4* s4 = (const float4*)(Wnext + kh*64*HF);
                    #pragma unroll
                    for (int i2 = 0; i2 < 2; ++i2) d4[t + i2*1024] = s4[t + i2*1024];
                }
                __syncthreads();
                if (act){
                    for (int k4 = 0; k4 < 16; ++k4){
                        float4 av[4];
                        #pragma unroll
                        for (int j=0;j<4;++j)
                            av[j] = *(const float4*)(P + ((size_t)g*k + r0 + j)*HF + kh*64 + k4*4);
                        #pragma unroll
                        for (int kk=0; kk<4; ++kk){
                            int kl = k4*4 + kk;
                            float4 w0 = *(const float4*)(sm.cv.Ws + kl*HF + cc0);
                            float4 w1 = *(const float4*)(sm.cv.Ws + kl*HF + cc0 + 64);
                            #pragma unroll
                            for (int j=0;j<4;++j){
                                float aa = reinterpret_cast<const float*>(&av[j])[kk];
                                acc[j][0] += aa*w0.x; acc[j][1] += aa*w0.y; acc[j][2] += aa*w0.z; acc[j][3] += aa*w0.w;
                                acc[j][4] += aa*w1.x; acc[j][5] += aa*w1.y; acc[j][6] += aa*w1.z; acc[j][7] += aa*w1.w;
                            }
                        }
                    }
                }
            }
            if (act){
                #pragma unroll
                for (int j=0;j<4;++j){
                    *(float4*)(Gnext + ((size_t)g*k + r0 + j)*HF + cc0)      = make_float4(acc[j][0],acc[j][1],acc[j][2],acc[j][3]);
                    *(float4*)(Gnext + ((size_t)g*k + r0 + j)*HF + cc0 + 64) = make_float4(acc[j][4],acc[j][5],acc[j][6],acc[j][7]);
                }
            }
        }
    }
    __syncthreads();
    {
        int f = (t & 31)*4;
        float4 s  = make_float4(0.f,0.f,0.f,0.f);
        float4 s2 = make_float4(0.f,0.f,0.f,0.f);
        float cb0 = cbNext[f], cb1 = cbNext[f+1], cb2 = cbNext[f+2], cb3 = cbNext[f+3];
        for (int l = t >> 5; l < k; l += 32){
            int v = g*k + l;
            float dv = dinvn[v];
            float4 y = *(const float4*)(Gnext + (size_t)v*HF + f);
            float4 acc = make_float4(0.f,0.f,0.f,0.f);
            int2 rb = rb2n[v];
            int e1 = rb.x + rb.y;
            for (int j = rb.x; j < e1; ++j){
                int2 e = csr[j];
                int sN = e.x & (Nn2 - 1);
                float en = __int_as_float(e.y);
                float4 h = *(const float4*)(Gnext + (size_t)sN*HF + f);
                acc.x += en*h.x; acc.y += en*h.y; acc.z += en*h.z; acc.w += en*h.w;
            }
            acc.x = y.x*dv*dv + dv*acc.x + cb0;
            acc.y = y.y*dv*dv + dv*acc.y + cb1;
            acc.z = y.z*dv*dv + dv*acc.z + cb2;
            acc.w = y.w*dv*dv + dv*acc.w + cb3;
            *(float4*)(Hnext + (size_t)v*HF + f) = acc;
            s.x += acc.x; s.y += acc.y; s.z += acc.z; s.w += acc.w;
            s2.x += acc.x*acc.x; s2.y += acc.y*acc.y; s2.z += acc.z*acc.z; s2.w += acc.w*acc.w;
        }
        int base = (t >> 5)*HF + f;
        __syncthreads();
        *(float4*)&sm.cv.red[base] = s;
        __syncthreads();
        if (t < 128){
            float a = 0.f;
            #pragma unroll
            for (int j = 0; j < 32; ++j) a += sm.cv.red[j*HF + t];
            atomicAdd(&stAcc[(g & 7)*256 + t], a);
        }
        __syncthreads();
        *(float4*)&sm.cv.red[base] = s2;
        __syncthreads();
        if (t < 128){
            float a = 0.f;
            #pragma unroll
            for (int j = 0; j < 32; ++j) a += sm.cv.red[j*HF + t];
            atomicAdd(&stAcc[(g & 7)*256 + 128 + t], a);
        }
    }
}

// ---------------- head tail kernels ----------------
__global__ __launch_bounds__(128) void k_head2(const float* __restrict__ t1, const float* __restrict__ gw,
                                               const float* __restrict__ gb, const float* __restrict__ W2,
                                               const float* __restrict__ b2, float* __restrict__ sh,
                                               float* __restrict__ t2){
    int r = blockIdx.x, t = threadIdx.x;
    int cc = t & 63, h = t >> 6;
    __shared__ float row[128];
    __shared__ float red[128];
    {
        float mean = sh[t] * (1.f/128.f);
        float var  = sh[128+t]*(1.f/128.f) - mean*mean;
        float iv   = rsqrtf(var + 1e-5f);
        float v = (t1[r*128+t] - mean)*iv*gw[t] + gb[t];
        row[t] = fmaxf(v, 0.f);
    }
    __syncthreads();
    float s = 0.f;
    #pragma unroll
    for (int kk = 0; kk < 64; ++kk)
        s += row[h*64+kk] * W2[(h*64+kk)*64 + cc];
    red[t] = s;
    __syncthreads();
    if (h == 0){
        float v = red[cc] + red[cc+64] + b2[cc];
        t2[r*64+cc] = v;
        atomicAdd(&sh[256+cc], v);
        atomicAdd(&sh[320+cc], v*v);
    }
}
__global__ __launch_bounds__(64) void k_head3(const float* __restrict__ t2, const float* __restrict__ gw,
                                              const float* __restrict__ gb, const float* __restrict__ W3,
                                              const float* __restrict__ b3, const float* __restrict__ sh,
                                              float* __restrict__ out){
    int r = blockIdx.x, t = threadIdx.x;
    float mean = sh[256+t]*(1.f/128.f);
    float var  = sh[320+t]*(1.f/128.f) - mean*mean;
    float iv   = rsqrtf(var + 1e-5f);
    float v = fmaxf((t2[r*64+t]-mean)*iv*gw[t] + gb[t], 0.f);
    float lg[10];
    #pragma unroll
    for (int j = 0; j < 10; ++j){
        float p = v * W3[t*10 + j];
        for (int off = 32; off; off >>= 1) p += __shfl_down(p, off);
        lg[j] = p;
    }
    if (t == 0){
        float m = -3.4e38f;
        #pragma unroll
        for (int j = 0; j < 10; ++j){ lg[j] += b3[j]; m = fmaxf(m, lg[j]); }
        float se = 0.f;
        #pragma unroll
        for (int j = 0; j < 10; ++j) se += expf(lg[j] - m);
        float l = logf(se) + m;
        #pragma unroll
        for (int j = 0; j < 10; ++j) out[r*10 + j] = lg[j] - l;
    }
}

extern "C" void kernel_launch(void* const* d_in, const int* in_sizes, int n_in,
                              void* d_out, int out_size, void* d_ws, size_t ws_size,
                              hipStream_t stream){
    const float* x     = (const float*)d_in[0];
    const float* convW = (const float*)d_in[1];
    const float* convb = (const float*)d_in[2];
    const float* bnW   = (const float*)d_in[3];
    const float* bnB   = (const float*)d_in[4];
    const float* bn7W  = (const float*)d_in[5];
    const float* bn7B  = (const float*)d_in[6];
    const float* attW  = (const float*)d_in[7];
    const float* theta = (const float*)d_in[8];
    const float* lin1W = (const float*)d_in[9];
    const float* lin1b = (const float*)d_in[10];
    const float* lin2W = (const float*)d_in[11];
    const float* lin2b = (const float*)d_in[12];
    const float* lin3W = (const float*)d_in[13];
    const float* lin3b = (const float*)d_in[14];
    const int*   src0  = (const int*)d_in[15];
    const int*   dst0  = (const int*)d_in[16];

    char* base = (char*)d_ws;
    size_t off = 0;
    auto take = [&](size_t bytes) -> void* {
        void* p = base + off;
        off = (off + bytes + 255) & ~(size_t)255;
        return p;
    };
    float* bufGP = (float*)take((size_t)N0G*HF*4);
    float* bufHA = (float*)take((size_t)N0G*HF*4);
    float* bufHB = (float*)take((size_t)(N0G/2)*HF*4);
    int*   srcw  = (int*)  take((size_t)ETOT*4);
    int*   dstw  = (int*)  take((size_t)ETOT*4);
    float* w     = (float*)take((size_t)ETOT*4);
    int2*  csr_p = (int2*) take((size_t)ETOT*8);
    int2*  rb2A  = (int2*) take((size_t)N0G*8);
    int2*  rb2B  = (int2*) take((size_t)N0G*8);
    float* dinvA = (float*)take((size_t)N0G*4);
    float* dinvB = (float*)take((size_t)N0G*4);
    float* st[3];
    st[0] = (float*)take(STSZ*4);
    st[1] = (float*)take(STSZ*4);
    st[2] = (float*)take(STSZ*4);
    float* gacc  = (float*)take((size_t)B_GRAPH*256*4);
    float* t1    = (float*)take((size_t)B_GRAPH*128*4);
    float* t2    = (float*)take((size_t)B_GRAPH*64*4);
    float* statsH= (float*)take(384*4);

    auto coef = [](int kk, float& ca, float& cc){
        double a = 1.0, b = 1.0;
        double c0 = 2.0*kk*(kk+a+b)*(2.0*kk+a+b-2.0);
        double c1 = (2.0*kk+a+b-1.0)*(2.0*kk+a+b)*(2.0*kk+a+b-2.0);
        double c3 = 2.0*(kk+a-1.0)*(kk+b-1.0)*(2.0*kk+a+b);
        ca = (float)(c1/c0); cc = (float)(-c3/c0);
    };
    float ca2, cc2, ca3, cc3;
    coef(2, ca2, cc2);
    coef(3, ca3, cc3);

    k_init_gemm<<<1024 + B_GRAPH, 256, 0, stream>>>(x, convW, bufGP,
                                                    src0, dst0, srcw, dstw, w, csr_p, rb2A, dinvA,
                                                    gacc, statsH, st[0], st[1], st[2]);
    k_prop_stats<<<N0G/8, 256, 0, stream>>>(bufGP, convb, rb2A, csr_p, dinvA, bufHA, st[0], 512, 6, N0G);

    float* G = bufGP + (size_t)4*1024*1024;   // G region for levels >= 1

    for (int i = 0; i < 5; ++i){
        int n = 512 >> i;
        int Nn = B_GRAPH*n;
        int2*  rb_cur = (i & 1) ? rb2B : rb2A;
        int2*  rb_nxt = (i & 1) ? rb2A : rb2B;
        float* dv_cur = (i & 1) ? dinvB : dinvA;
        float* dv_nxt = (i & 1) ? dinvA : dinvB;
        float* Hcur = (i & 1) ? bufHB : bufHA;
        float* Hnxt = (i & 1) ? bufHA : bufHB;
        int wnext = (i < 4) ? (i + 1) : 4;

        k_graph<<<B_GRAPH, 1024, 0, stream>>>(Hcur, st[i % 3], bnW + i*HF, bnB + i*HF, attW + i*HF,
                                              theta + i*4, rb_cur, csr_p, dv_cur,
                                              srcw, dstw, w, bufGP, gacc, rb_nxt, dv_nxt,
                                              st[(i + 2) % 3], st[(i + 1) % 3],
                                              convW + (size_t)wnext*HF*HF, convb + wnext*HF,
                                              G, Hnxt,
                                              lin1W, lin1b, t1, statsH,
                                              1.0f/(float)Nn, ca2, cc2, ca3, cc3, n, (i == 4) ? 1 : 0);
    }

    k_head2<<<B_GRAPH, 128, 0, stream>>>(t1, bnW + 5*HF, bnB + 5*HF, lin2W, lin2b, statsH, t2);
    k_head3<<<B_GRAPH, 64, 0, stream>>>(t2, bn7W, bn7B, lin3W, lin3b, statsH, (float*)d_out);
}